// Round 3
// baseline (810.318 us; speedup 1.0000x reference)
//
#include <hip/hip_runtime.h>
#include <hip/hip_bf16.h>

#define H 128
#define IDX_CAP 2048  // per-wave staged edge-index capacity (ints)

using bf16x8  = __attribute__((ext_vector_type(8))) short;  // 8 bf16 = 4 VGPRs
using floatx4 = __attribute__((ext_vector_type(4))) float;

static __device__ __forceinline__ short f2bf(float f) {
  union { float f; unsigned u; } v; v.f = f;
  unsigned r = v.u + 0x7fffu + ((v.u >> 16) & 1u);  // RNE
  return (short)(r >> 16);
}
static __device__ __forceinline__ float bf2f(short s) {
  union { unsigned u; float f; } v; v.u = ((unsigned)(unsigned short)s) << 16;
  return v.f;
}

// ---- degree counts (int) ----
__global__ void count_edges(const int* __restrict__ src, const int* __restrict__ dst,
                            int E, int* __restrict__ cnt_s, int* __restrict__ cnt_d) {
  int e = blockIdx.x * blockDim.x + threadIdx.x;
  if (e >= E) return;
  atomicAdd(&cnt_s[src[e]], 1);
  atomicAdd(&cnt_d[dst[e]], 1);
}

// ---- 3-kernel exclusive scan over 4 contiguous count arrays ----
__global__ __launch_bounds__(256) void scan_k1(const int* __restrict__ cnt, int* __restrict__ off,
                                               int* __restrict__ bsums, int4 starts, int4 lens) {
  int a = blockIdx.y;
  int start = ((const int*)&starts)[a];
  int len   = ((const int*)&lens)[a];
  int chunk = blockIdx.x * 1024;
  if (chunk >= len) return;
  const int* in = cnt + start;
  int* out = off + start;
  int tid = threadIdx.x;
  int base = chunk + tid * 4;
  int v[4];
#pragma unroll
  for (int j = 0; j < 4; ++j) v[j] = (base + j < len) ? in[base + j] : 0;
  int s = v[0] + v[1] + v[2] + v[3];
  __shared__ int lds[256];
  lds[tid] = s; __syncthreads();
  for (int o = 1; o < 256; o <<= 1) {
    int t = (tid >= o) ? lds[tid - o] : 0;
    __syncthreads();
    lds[tid] += t;
    __syncthreads();
  }
  int run = lds[tid] - s;  // exclusive prefix of this thread's 4
#pragma unroll
  for (int j = 0; j < 4; ++j) { if (base + j < len) out[base + j] = run; run += v[j]; }
  if (tid == 255) bsums[a * 256 + blockIdx.x] = lds[255];
}

__global__ __launch_bounds__(256) void scan_k2(int* __restrict__ bsums, int4 lens) {
  int a = blockIdx.x;
  int len = ((const int*)&lens)[a];
  int nb = (len + 1023) >> 10;
  int tid = threadIdx.x;
  int s = (tid < nb) ? bsums[a * 256 + tid] : 0;  // guard: slots >= nb are poisoned
  __shared__ int lds[256];
  lds[tid] = s; __syncthreads();
  for (int o = 1; o < 256; o <<= 1) {
    int t = (tid >= o) ? lds[tid - o] : 0;
    __syncthreads();
    lds[tid] += t;
    __syncthreads();
  }
  bsums[a * 256 + tid] = lds[tid] - s;
}

__global__ __launch_bounds__(256) void scan_k3(int* __restrict__ off, const int* __restrict__ bsums,
                                               int4 starts, int4 lens) {
  int a = blockIdx.y;
  int start = ((const int*)&starts)[a];
  int len   = ((const int*)&lens)[a];
  int chunk = blockIdx.x * 1024;
  if (chunk >= len) return;
  int add = bsums[a * 256 + blockIdx.x];
  int* out = off + start;
  int base = chunk + threadIdx.x * 4;
#pragma unroll
  for (int j = 0; j < 4; ++j) if (base + j < len) out[base + j] += add;
}

// ---- CSR fill (both directions of one relation) ----
__global__ void fill_csr(const int* __restrict__ src, const int* __restrict__ dst, int E,
                         const int* __restrict__ off_d, int* __restrict__ cur_d, int* __restrict__ sort_d,
                         const int* __restrict__ off_s, int* __restrict__ cur_s, int* __restrict__ sort_s) {
  int e = blockIdx.x * blockDim.x + threadIdx.x;
  if (e >= E) return;
  int s = src[e], d = dst[e];
  sort_d[off_d[d] + atomicAdd(&cur_d[d], 1)] = s;  // neighbors of dst node (src ids)
  sort_s[off_s[s] + atomicAdd(&cur_s[s], 1)] = d;  // neighbors of src node (dst ids)
}

// ---- fp32 -> bf16 streaming convert ----
__global__ void cvt_bf16(const float* __restrict__ in, short* __restrict__ out, int n) {
  int idx = (blockIdx.x * blockDim.x + threadIdx.x) * 4;
  if (idx >= n) return;
  float4 v = *(const float4*)(in + idx);
  short4 o = { f2bf(v.x), f2bf(v.y), f2bf(v.z), f2bf(v.w) };
  *(short4*)(out + idx) = o;
}

// ---- weight prep: bf16 convert, combine Wr pair and bias pair per (layer,type).
// Weights written in MFMA B-fragment order:
//   fragment (jt,kk), lane l holds 8 bf16 of W[(jt*16 + (l&15))][kk*32 + (l>>4)*8 + j]
//   stored at ((jt*4+kk)*64 + l)*8 + j
static __device__ __forceinline__ int wswz(int e) {
  int n = e >> 7, k = e & 127;          // W row-major [n][k]
  int jt = n >> 4, r = n & 15;
  int kk = k >> 5, q = (k >> 3) & 3, j = k & 7;
  return (((jt * 4 + kk) * 64 + q * 16 + r) << 3) + j;
}
__global__ void prep_weights(const float* __restrict__ W_l, const float* __restrict__ b_l,
                             const float* __restrict__ W_r,
                             short* __restrict__ Wbf, float* __restrict__ bc) {
  int i = blockIdx.x * blockDim.x + threadIdx.x;
  if (i >= 4 * 16384) return;
  int s = i >> 14, e = i & 16383;
  int l = s >> 1, t = s & 1;
  int rA = t ? 1 : 0, rB = t ? 3 : 2;
  const float* WA = W_l + ((size_t)(l * 4 + rA) << 14);
  const float* WB = W_l + ((size_t)(l * 4 + rB) << 14);
  const float* RA = W_r + ((size_t)(l * 4 + rA) << 14);
  const float* RB = W_r + ((size_t)(l * 4 + rB) << 14);
  short* o = Wbf + (size_t)s * 3 * 16384;
  int d = wswz(e);
  o[d]             = f2bf(WA[e]);
  o[16384 + d]     = f2bf(WB[e]);
  o[2 * 16384 + d] = f2bf(RA[e] + RB[e]);
  if (e < H) bc[s * H + e] = b_l[(l * 4 + rA) * H + e] + b_l[(l * 4 + rB) * H + e];
}

// ---- fully fused SAGE layer: segment-mean + out = mV@WA.T + mL@WB.T + x@WRc.T + b [,ReLU]
// One launch covers posts AND users. 256 blocks x 512 threads, 160 KB LDS:
//   96 KB: 3 weight matrices in B-fragment order (staged once, ONE barrier)
//   64 KB: 8 KB/wave edge-index buffer (indices ride lgkmcnt, so index waits
//          never drain in-flight vmcnt feature gathers)
// Each wave owns 32-row groups. Gather uses 16-rows-per-lane-group mapping:
// lane (r=lane&15, quad=lane>>4) accumulates row r's k-slice [quad*8 + kk*32]
// in fp32 -> mean rounds to bf16 directly into the MFMA A-fragment. No LDS
// transpose, no mV/mL intermediate arrays (saves ~614 MB HBM round-trip).
// Depth-2 (2-edge) software pipeline: 8x16B gathers in flight per lane.
// A frag: A[m=lane&15][k=quad*8+j]; B frag: B[k][n=lane&15]=W[n][k];
// C/D: col=lane&15, row=quad*4+reg.
__global__ __launch_bounds__(512, 2) void fused_layer(
    const short* __restrict__ xgA, const short* __restrict__ xbA,
    const int* __restrict__ sVA, const int* __restrict__ oVA, const int* __restrict__ cVA,
    const int* __restrict__ sLA, const int* __restrict__ oLA, const int* __restrict__ cLA,
    const short* __restrict__ WAp, const float* __restrict__ biasA,
    float* __restrict__ o32A, short* __restrict__ o16A, int NA, int nbA,
    const short* __restrict__ xgB, const short* __restrict__ xbB,
    const int* __restrict__ sVB, const int* __restrict__ oVB, const int* __restrict__ cVB,
    const int* __restrict__ sLB, const int* __restrict__ oLB, const int* __restrict__ cLB,
    const short* __restrict__ WBp, const float* __restrict__ biasB,
    float* __restrict__ o32B, short* __restrict__ o16B, int NB, int relu) {
  extern __shared__ short smem[];          // 96 KB W + 64 KB idx
  short* Wlds = smem;                      // 3 * 16384 shorts
  int* idxLds = (int*)(smem + 3 * 16384);  // 8 waves * 2048 ints

  int b = blockIdx.x;
  const short *xg, *xb, *W; const int *sV, *oV, *cV, *sL, *oL, *cL;
  const float* bias; float* out32; short* out16; int N, nbPart, bLoc;
  if (b < nbA) {
    xg = xgA; xb = xbA; sV = sVA; oV = oVA; cV = cVA; sL = sLA; oL = oLA; cL = cLA;
    W = WAp; bias = biasA; out32 = o32A; out16 = o16A; N = NA; nbPart = nbA; bLoc = b;
  } else {
    xg = xgB; xb = xbB; sV = sVB; oV = oVB; cV = cVB; sL = sLB; oL = oLB; cL = cLB;
    W = WBp; bias = biasB; out32 = o32B; out16 = o16B; N = NB;
    nbPart = gridDim.x - nbA; bLoc = b - nbA;
  }

  int tid = threadIdx.x;
  // stage all 3 weight matrices (6144 x 16B chunks), coalesced linear copy
#pragma unroll
  for (int it = 0; it < 12; ++it) {
    int c = it * 512 + tid;
    *(bf16x8*)(Wlds + (size_t)c * 8) = *(const bf16x8*)(W + (size_t)c * 8);
  }
  __syncthreads();  // the ONLY barrier

  int wave = tid >> 6, lane = tid & 63;
  int r = lane & 15, quad = lane >> 4;
  int* myIdx = idxLds + wave * IDX_CAP;

  float bias_r[8];
#pragma unroll
  for (int jt = 0; jt < 8; ++jt) bias_r[jt] = bias[jt * 16 + r];

  int nrgTot = (N + 31) >> 5;
  int wStride = nbPart * 8;
  int wBase = bLoc * 8 + wave;

  floatx4 acc[2][8];

  for (int rg = wBase; rg < nrgTot; rg += wStride) {
    int rowb = rg << 5;

    // ---- xb A-frags: issue early, consumed by MFMA m=2 at the end ----
    bf16x8 afX[2][4];
#pragma unroll
    for (int t = 0; t < 2; ++t) {
      int row = rowb + t * 16 + r;
      row = row < N ? row : N - 1;
      const short* Xr = xb + (size_t)row * H + quad * 8;
#pragma unroll
      for (int kk = 0; kk < 4; ++kk) afX[t][kk] = *(const bf16x8*)(Xr + kk * 32);
    }

    // ---- stage this rowgroup's V and L edge indices into LDS (wave-private) ----
    int rbL = rowb + 31; rbL = rbL < N ? rbL : N - 1;
    int OV0 = oV[rowb];
    int lenV = oV[rbL] + cV[rbL] - OV0;
    int OL0 = oL[rowb];
    int lenL = oL[rbL] + cL[rbL] - OL0;
    int capV = lenV < IDX_CAP ? lenV : IDX_CAP;
    int rem = IDX_CAP - capV;
    int capL = lenL < rem ? lenL : rem;
    for (int k = lane; k < capV; k += 64) myIdx[k] = sV[OV0 + k];
    for (int k = lane; k < capL; k += 64) myIdx[capV + k] = sL[OL0 + k];

#pragma unroll
    for (int t = 0; t < 2; ++t)
#pragma unroll
      for (int j = 0; j < 8; ++j) acc[t][j] = floatx4{0.f, 0.f, 0.f, 0.f};

    bf16x8 afm[2][4];  // mean A-frags for current relation (reused V then L)

    // gather+mean for one relation into afm; depth-2 edge pipeline
    auto gatherRel = [&](const int* __restrict__ offA, const int* __restrict__ cntA,
                         const int* __restrict__ sG, int O0, int base, int cap) {
#pragma unroll
      for (int t = 0; t < 2; ++t) {
        int row = rowb + t * 16 + r;
        int node = row < N ? row : N - 1;
        int o = offA[node], n = cntA[node];
        int lo = o - O0;
        float ag[4][8];
#pragma unroll
        for (int kk = 0; kk < 4; ++kk)
#pragma unroll
          for (int j = 0; j < 8; ++j) ag[kk][j] = 0.f;

        auto gidx = [&](int i) -> int {
          int li = lo + i;
          return (li < cap) ? myIdx[base + li] : sG[o + i];  // LDS fast path (always taken in practice)
        };

        bf16x8 pA[4], pB[4];
        if (n > 0) {
          const short* xr = xg + (size_t)gidx(0) * H + quad * 8;
#pragma unroll
          for (int kk = 0; kk < 4; ++kk) pA[kk] = *(const bf16x8*)(xr + kk * 32);
        }
        if (n > 1) {
          const short* xr = xg + (size_t)gidx(1) * H + quad * 8;
#pragma unroll
          for (int kk = 0; kk < 4; ++kk) pB[kk] = *(const bf16x8*)(xr + kk * 32);
        }
        for (int i = 0; i < n; i += 2) {
          bf16x8 nA[4], nB[4];
          if (i + 2 < n) {
            const short* xr = xg + (size_t)gidx(i + 2) * H + quad * 8;
#pragma unroll
            for (int kk = 0; kk < 4; ++kk) nA[kk] = *(const bf16x8*)(xr + kk * 32);
          }
          if (i + 3 < n) {
            const short* xr = xg + (size_t)gidx(i + 3) * H + quad * 8;
#pragma unroll
            for (int kk = 0; kk < 4; ++kk) nB[kk] = *(const bf16x8*)(xr + kk * 32);
          }
#pragma unroll
          for (int kk = 0; kk < 4; ++kk)
#pragma unroll
            for (int j = 0; j < 8; ++j) ag[kk][j] += bf2f(pA[kk][j]);
          if (i + 1 < n) {
#pragma unroll
            for (int kk = 0; kk < 4; ++kk)
#pragma unroll
              for (int j = 0; j < 8; ++j) ag[kk][j] += bf2f(pB[kk][j]);
          }
#pragma unroll
          for (int kk = 0; kk < 4; ++kk) { pA[kk] = nA[kk]; pB[kk] = nB[kk]; }
        }
        float rin = 1.0f / fmaxf((float)n, 1.0f);
#pragma unroll
        for (int kk = 0; kk < 4; ++kk) {
          bf16x8 w;
#pragma unroll
          for (int j = 0; j < 8; ++j) w[j] = f2bf(ag[kk][j] * rin);
          afm[t][kk] = w;
        }
      }
    };

    auto mfmaMat = [&](int m, bf16x8 (&af)[2][4]) {
      const short* Wm = Wlds + m * 16384;
#pragma unroll
      for (int kk = 0; kk < 4; ++kk) {
#pragma unroll
        for (int jt = 0; jt < 8; ++jt) {
          bf16x8 bfR = *(const bf16x8*)(Wm + (size_t)((jt * 4 + kk) * 64 + lane) * 8);
          acc[0][jt] = __builtin_amdgcn_mfma_f32_16x16x32_bf16(af[0][kk], bfR, acc[0][jt], 0, 0, 0);
          acc[1][jt] = __builtin_amdgcn_mfma_f32_16x16x32_bf16(af[1][kk], bfR, acc[1][jt], 0, 0, 0);
        }
      }
    };

    gatherRel(oV, cV, sV, OV0, 0, capV);     // viewed means -> afm
    mfmaMat(0, afm);
    gatherRel(oL, cL, sL, OL0, capV, capL);  // liked means -> afm
    mfmaMat(1, afm);
    mfmaMat(2, afX);                         // self transform

    // ---- epilogue ----
#pragma unroll
    for (int t = 0; t < 2; ++t) {
#pragma unroll
      for (int jt = 0; jt < 8; ++jt) {
        int ocol = jt * 16 + r;
        float bv = bias_r[jt];
#pragma unroll
        for (int g = 0; g < 4; ++g) {
          int orow = rowb + t * 16 + quad * 4 + g;
          if (orow < N) {
            float v = acc[t][jt][g] + bv;
            if (relu) v = fmaxf(v, 0.f);
            if (out32) out32[(size_t)orow * H + ocol] = v;
            else       out16[(size_t)orow * H + ocol] = f2bf(v);
          }
        }
      }
    }
  }
}

extern "C" void kernel_launch(void* const* d_in, const int* in_sizes, int n_in,
                              void* d_out, int out_size, void* d_ws, size_t ws_size,
                              hipStream_t stream) {
  const float* emb_user = (const float*)d_in[0];
  const float* emb_post = (const float*)d_in[1];
  const float* W_l = (const float*)d_in[2];
  const float* b_l = (const float*)d_in[3];
  const float* W_r = (const float*)d_in[4];
  const int* ev_s = (const int*)d_in[5];
  const int* ev_d = (const int*)d_in[6];
  const int* el_s = (const int*)d_in[7];
  const int* el_d = (const int*)d_in[8];

  const int NU = in_sizes[0] / H;
  const int NP = in_sizes[1] / H;
  const int EV = in_sizes[5];
  const int EL = in_sizes[7];
  const int T = 2 * NP + 2 * NU;
  const size_t NUH = (size_t)NU * H, NPH = (size_t)NP * H;

  // workspace carve (256B-aligned bumps)
  char* p = (char*)d_ws;
  auto alloc = [&](size_t bytes) -> void* {
    void* q = (void*)p; p += (bytes + 255) & ~(size_t)255; return q;
  };
  int*   cnt   = (int*)alloc((size_t)T * 4);
  int*   cur   = (int*)alloc((size_t)T * 4);
  int*   off   = (int*)alloc((size_t)T * 4);
  int*   bsums = (int*)alloc(4 * 256 * 4);
  int*   sV_p  = (int*)alloc((size_t)EV * 4);
  int*   sV_u  = (int*)alloc((size_t)EV * 4);
  int*   sL_p  = (int*)alloc((size_t)EL * 4);
  int*   sL_u  = (int*)alloc((size_t)EL * 4);
  short* Wbf   = (short*)alloc((size_t)4 * 3 * 16384 * 2);
  float* bc    = (float*)alloc(4 * H * 4);
  short* xbf_u  = (short*)alloc(NUH * 2);
  short* xbf_p  = (short*)alloc(NPH * 2);
  short* xbf1_u = (short*)alloc(NUH * 2);
  short* xbf1_p = (short*)alloc(NPH * 2);

  float* out_u_final = (float*)d_out;
  float* out_p_final = (float*)d_out + NUH;

  // count-array index order: {V_p:0, L_p:NP, V_u:2NP, L_u:2NP+NU}
  const int oV_p = 0, oL_p = NP, oV_u = 2 * NP, oL_u = 2 * NP + NU;

  hipMemsetAsync(cnt, 0, (size_t)T * 4, stream);
  hipMemsetAsync(cur, 0, (size_t)T * 4, stream);
  count_edges<<<(EV + 255) / 256, 256, 0, stream>>>(ev_s, ev_d, EV, cnt + oV_u, cnt + oV_p);
  count_edges<<<(EL + 255) / 256, 256, 0, stream>>>(el_s, el_d, EL, cnt + oL_u, cnt + oL_p);

  int4 starts = { oV_p, oL_p, oV_u, oL_u };
  int4 lens   = { NP, NP, NU, NU };
  int maxb = ((NP > NU ? NP : NU) + 1023) / 1024;
  dim3 gscan(maxb, 4, 1);
  scan_k1<<<gscan, 256, 0, stream>>>(cnt, off, bsums, starts, lens);
  scan_k2<<<4, 256, 0, stream>>>(bsums, lens);
  scan_k3<<<gscan, 256, 0, stream>>>(off, bsums, starts, lens);

  fill_csr<<<(EV + 255) / 256, 256, 0, stream>>>(ev_s, ev_d, EV,
                                                 off + oV_p, cur + oV_p, sV_p,
                                                 off + oV_u, cur + oV_u, sV_u);
  fill_csr<<<(EL + 255) / 256, 256, 0, stream>>>(el_s, el_d, EL,
                                                 off + oL_p, cur + oL_p, sL_p,
                                                 off + oL_u, cur + oL_u, sL_u);

  cvt_bf16<<<((int)(NUH / 4) + 255) / 256, 256, 0, stream>>>(emb_user, xbf_u, (int)NUH);
  cvt_bf16<<<((int)(NPH / 4) + 255) / 256, 256, 0, stream>>>(emb_post, xbf_p, (int)NPH);
  prep_weights<<<(4 * 16384 + 255) / 256, 256, 0, stream>>>(W_l, b_l, W_r, Wbf, bc);

  // allow 160 KB dynamic LDS for the fused layer kernel
  hipFuncSetAttribute((const void*)fused_layer, hipFuncAttributeMaxDynamicSharedMemorySize,
                      160 * 1024);

  // block split: both parts have (EV+EL) gather-edges; fixed per-row work ~ 3 units
  long long wP = (long long)(EV + EL) + 3LL * NP;
  long long wU = (long long)(EV + EL) + 3LL * NU;
  int nbP = (int)((256LL * wP) / (wP + wU));
  if (nbP < 1) nbP = 1;
  if (nbP > 255) nbP = 255;

  for (int l = 0; l < 2; ++l) {
    const short* xu = l ? xbf1_u : xbf_u;
    const short* xp = l ? xbf1_p : xbf_p;
    const short* Wpost = Wbf + (size_t)(l * 2 + 0) * 3 * 16384;
    const short* Wuser = Wbf + (size_t)(l * 2 + 1) * 3 * 16384;
    const float* bpost = bc + (l * 2 + 0) * H;
    const float* buser = bc + (l * 2 + 1) * H;

    fused_layer<<<256, 512, 160 * 1024, stream>>>(
        // part A: posts (gather user features into post rows)
        xu, xp, sV_p, off + oV_p, cnt + oV_p, sL_p, off + oL_p, cnt + oL_p,
        Wpost, bpost, l ? out_p_final : nullptr, l ? nullptr : xbf1_p, NP, nbP,
        // part B: users (gather post features into user rows)
        xp, xu, sV_u, off + oV_u, cnt + oV_u, sL_u, off + oL_u, cnt + oL_u,
        Wuser, buser, l ? out_u_final : nullptr, l ? nullptr : xbf1_u, NU, l == 0);
  }
}